// Round 10
// baseline (667.866 us; speedup 1.0000x reference)
//
#include <hip/hip_runtime.h>
#include <math.h>

#define Bsz 4
#define Cch 256
#define Npt 2048
#define Hh  4
#define NL  4
#define BN_CNT (Bsz * Npt)   // 8192
#define EPSV 1e-5f
#define NROW (16 * Npt)      // 32768 attention rows total (bh * Npt)
#define L2E 1.44269504f
#define GB_BLOCKS 512u       // k_gemm_bn grid size (must equal g4 product)

typedef _Float16 f16x8 __attribute__((ext_vector_type(8)));
typedef _Float16 f16x4 __attribute__((ext_vector_type(4)));
typedef float    f32x4 __attribute__((ext_vector_type(4)));

__device__ __forceinline__ float fexp2(float x) { return __builtin_amdgcn_exp2f(x); }

// ---------------- init: xyz embedding + weight cast + bnacc/cnt zero (merged) ----------------
__global__ void k_init(const float* __restrict__ xyz, const float* __restrict__ pw,
                       const float* __restrict__ pb, float* __restrict__ emb,
                       const float* __restrict__ c1w, const float* __restrict__ qkw,
                       const float* __restrict__ vw, const float* __restrict__ tw,
                       _Float16* __restrict__ o, float* __restrict__ bnacc,
                       unsigned* __restrict__ cnt) {
    int idx = blockIdx.x * 256 + threadIdx.x;   // 0 .. NE-1 (2,097,152)
    int n = idx & (Npt - 1);
    int c = (idx >> 11) & (Cch - 1);
    int b = idx >> 19;
    const float* xz = xyz + (b * Npt + n) * 3;
    emb[idx] = pw[c * 3 + 0] * xz[0] + pw[c * 3 + 1] * xz[1] + pw[c * 3 + 2] * xz[2] + pb[c];
    if (idx < 5 * 512) bnacc[idx] = 0.f;     // 5 slots x (sum[256], sum2[256])
    if (idx < 5) cnt[idx] = 0u;              // 5 barrier counters (one per gemm_bn call)
    if (idx < 851968) {
        const float* src; int off;
        if (idx < 65536)         { src = c1w; off = idx; }
        else if (idx < 327680)   { src = qkw; off = idx - 65536; }
        else if (idx < 589824)   { src = vw;  off = idx - 327680; }
        else                     { src = tw;  off = idx - 589824; }
        o[idx] = (_Float16)src[off];
    }
}

// ---------------- transpose + cast x -> XT[b][n][c] (entry only) ----------------
__global__ __launch_bounds__(256) void k_fuse_t(const float* __restrict__ in,
        _Float16* __restrict__ XT) {
    __shared__ _Float16 Tt[64][72];
    const int b = blockIdx.z, c0 = blockIdx.y * 64, n0 = blockIdx.x * 64;
    const int t = threadIdx.x;
    const int cl = t >> 2, ns = (t & 3) * 16;
    const float* ip = in + ((size_t)(b * Cch + c0 + cl) * Npt) + n0 + ns;
    #pragma unroll
    for (int g = 0; g < 4; ++g) {
        float4 v = *(const float4*)(ip + g * 4);
        Tt[ns + g * 4 + 0][cl] = (_Float16)v.x;
        Tt[ns + g * 4 + 1][cl] = (_Float16)v.y;
        Tt[ns + g * 4 + 2][cl] = (_Float16)v.z;
        Tt[ns + g * 4 + 3][cl] = (_Float16)v.w;
    }
    __syncthreads();
    int nl = t >> 2, cs = (t & 3) * 16;
    _Float16* op = XT + ((size_t)(b * Npt + n0 + nl) * Cch) + c0 + cs;
    #pragma unroll
    for (int g = 0; g < 4; ++g)
        *(f16x4*)(op + g * 4) = *(f16x4*)&Tt[nl][cs + g * 4];
}

// ---------------- FUSED MFMA GEMM + BN + relu + residual + out + transpose -> XT ----------------
// Replaces the k_gemm_mfma -> vbuf -> k_bn_fuse pair. The block keeps its 64x64 fp32
// tile in LDS (EpF); BN's grid-wide stats dependency is satisfied by an IN-KERNEL device
// barrier: per-block stat atomics drain at __syncthreads (compiler emits vmcnt(0) before
// s_barrier), tid0 bumps a per-invocation counter and spins (agent-scope acquire load +
// s_sleep) until all GB_BLOCKS arrive. Deadlock-safe: grid 512 = 2 blocks/CU exactly;
// launch_bounds(256,2) (VGPR<=128) + 26.7KB LDS guarantee >=2 blocks/CU co-resident.
// Stats read via __hip_atomic_load agent-scope (bypasses non-coherent L1). Saves the
// 16MB vbuf round-trip + one dispatch per pair. Math bit-identical to the split version.
__global__ __launch_bounds__(256, 2) void k_gemm_bn(const _Float16* __restrict__ Wb,
        const _Float16* __restrict__ XT, const float* __restrict__ bias,
        float* __restrict__ bnacc, unsigned* __restrict__ cnt,
        const float* __restrict__ g, const float* __restrict__ bt,
        const float* __restrict__ emb, const float* __restrict__ resid,
        float* __restrict__ hout, float* __restrict__ out, _Float16* __restrict__ XTo,
        int layer) {
    __shared__ float EpF[64][68];
    __shared__ _Float16 Tt[64][72];
    const int b = blockIdx.z, o0 = blockIdx.y * 64, n0 = blockIdx.x * 64;
    const int tid = threadIdx.x, w = tid >> 6, quad = (tid >> 4) & 3, tx = tid & 15;
    const _Float16* Arow = Wb + (o0 + w * 16 + tx) * Cch + quad * 8;
    const _Float16* Brow = XT + ((size_t)(b * Npt + n0 + tx) * Cch) + quad * 8;
    f32x4 acc[4];
    #pragma unroll
    for (int s = 0; s < 4; ++s) acc[s] = (f32x4){0.f, 0.f, 0.f, 0.f};
    for (int k0 = 0; k0 < Cch; k0 += 32) {
        f16x8 a = *(const f16x8*)(Arow + k0);
        #pragma unroll
        for (int s = 0; s < 4; ++s) {
            f16x8 bb = *(const f16x8*)(Brow + s * 16 * Cch + k0);
            acc[s] = __builtin_amdgcn_mfma_f32_16x16x32_f16(a, bb, acc[s], 0, 0, 0);
        }
    }
    float bv[4];
    {
        int ob = o0 + w * 16 + quad * 4;
        if (bias) { bv[0] = bias[ob]; bv[1] = bias[ob + 1]; bv[2] = bias[ob + 2]; bv[3] = bias[ob + 3]; }
        else bv[0] = bv[1] = bv[2] = bv[3] = 0.f;
    }
    #pragma unroll
    for (int s = 0; s < 4; ++s) {
        int ol = w * 16 + quad * 4, nl = s * 16 + tx;
        EpF[ol + 0][nl] = acc[s][0] + bv[0];
        EpF[ol + 1][nl] = acc[s][1] + bv[1];
        EpF[ol + 2][nl] = acc[s][2] + bv[2];
        EpF[ol + 3][nl] = acc[s][3] + bv[3];
    }
    __syncthreads();
    // ---- BN partial stats from EpF (identical math/order to the split version) ----
    {
        int row = tid >> 2, seg = (tid & 3) * 16;
        float s1 = 0.f, s2 = 0.f;
        #pragma unroll
        for (int gi = 0; gi < 4; ++gi) {
            float4 v = *(float4*)&EpF[row][seg + gi * 4];
            s1 += v.x + v.y + v.z + v.w;
            s2 += v.x * v.x + v.y * v.y + v.z * v.z + v.w * v.w;
        }
        s1 += __shfl_xor(s1, 1); s2 += __shfl_xor(s2, 1);
        s1 += __shfl_xor(s1, 2); s2 += __shfl_xor(s2, 2);
        if ((tid & 3) == 0) {
            atomicAdd(&bnacc[o0 + row], s1);
            atomicAdd(&bnacc[256 + o0 + row], s2);
        }
    }
    // ---- device-wide barrier (all stat atomics of all blocks complete past this) ----
    __syncthreads();                       // drains this block's atomics (vmcnt(0) + s_barrier)
    if (tid == 0) {
        __threadfence();
        atomicAdd(cnt, 1u);
        while (__hip_atomic_load(cnt, __ATOMIC_ACQUIRE, __HIP_MEMORY_SCOPE_AGENT) < GB_BLOCKS)
            __builtin_amdgcn_s_sleep(2);
    }
    __syncthreads();
    // ---- BN epilogue from LDS tile ----
    const int cl = tid >> 2, ns = (tid & 3) * 16;
    const int c = o0 + cl;
    const float smn = __hip_atomic_load(&bnacc[c], __ATOMIC_RELAXED, __HIP_MEMORY_SCOPE_AGENT);
    const float sv2 = __hip_atomic_load(&bnacc[256 + c], __ATOMIC_RELAXED, __HIP_MEMORY_SCOPE_AGENT);
    const float mn = smn * (1.f / BN_CNT);
    const float var = sv2 * (1.f / BN_CNT) - mn * mn;
    const float is = rsqrtf(var + EPSV);
    const float gg = g[c], bb = bt[c];
    const size_t rowoff = ((size_t)(b * Cch + c) * Npt) + n0 + ns;
    const float* ep = emb + rowoff;
    const float* rp = resid ? resid + rowoff : nullptr;
    float* hp = hout + rowoff;
    float* op = out ? out + (size_t)b * (NL * Cch * Npt) + (size_t)(layer * Cch + c) * Npt + n0 + ns
                    : nullptr;
    #pragma unroll
    for (int gi = 0; gi < 4; ++gi) {
        float4 v = *(const float4*)&EpF[cl][ns + gi * 4];
        float4 y;
        y.x = fmaxf(gg * (v.x - mn) * is + bb, 0.f);
        y.y = fmaxf(gg * (v.y - mn) * is + bb, 0.f);
        y.z = fmaxf(gg * (v.z - mn) * is + bb, 0.f);
        y.w = fmaxf(gg * (v.w - mn) * is + bb, 0.f);
        if (rp) {
            float4 r = *(const float4*)(rp + gi * 4);
            y.x += r.x; y.y += r.y; y.z += r.z; y.w += r.w;
        }
        *(float4*)(hp + gi * 4) = y;
        if (op) *(float4*)(op + gi * 4) = y;
        float4 e = *(const float4*)(ep + gi * 4);
        Tt[ns + gi * 4 + 0][cl] = (_Float16)(y.x + e.x);
        Tt[ns + gi * 4 + 1][cl] = (_Float16)(y.y + e.y);
        Tt[ns + gi * 4 + 2][cl] = (_Float16)(y.z + e.z);
        Tt[ns + gi * 4 + 3][cl] = (_Float16)(y.w + e.w);
    }
    __syncthreads();
    int nl = tid >> 2, cs = (tid & 3) * 16;
    _Float16* xp = XTo + ((size_t)(b * Npt + n0 + nl) * Cch) + o0 + cs;
    #pragma unroll
    for (int gi = 0; gi < 4; ++gi)
        *(f16x4*)(xp + gi * 4) = *(f16x4*)&Tt[nl][cs + gi * 4];
}

// ---------------- fused qk + v GEMM, 64o x 128n tiles: y<4 -> Qg/Kt (swizzled),
// y>=4 -> Vb fp16 (permuted columns). Grid (16,8,4)=512, 2 blocks/CU.
__global__ __launch_bounds__(256) void k_gemm_qkv(const _Float16* __restrict__ Wqk,
        const _Float16* __restrict__ Wv, const _Float16* __restrict__ XT,
        const float* __restrict__ vbias, _Float16* __restrict__ Vb,
        _Float16* __restrict__ Qg, _Float16* __restrict__ Kt) {
    __shared__ _Float16 EpB[64][136];
    const int b = blockIdx.z, y = blockIdx.y, n0 = blockIdx.x * 128;
    const int isV = (y >= 4);
    const int o0 = (isV ? (y - 4) : y) * 64;
    const _Float16* Wb = isV ? Wv : Wqk;
    const int tid = threadIdx.x, w = tid >> 6, quad = (tid >> 4) & 3, tx = tid & 15;
    const _Float16* Arow = Wb + (o0 + w * 16 + tx) * Cch + quad * 8;
    const _Float16* Brow = XT + ((size_t)(b * Npt + n0 + tx) * Cch) + quad * 8;
    f32x4 acc[8];
    #pragma unroll
    for (int s = 0; s < 8; ++s) acc[s] = (f32x4){0.f, 0.f, 0.f, 0.f};
    for (int k0 = 0; k0 < Cch; k0 += 32) {
        f16x8 a = *(const f16x8*)(Arow + k0);
        #pragma unroll
        for (int s = 0; s < 8; ++s) {
            f16x8 bb = *(const f16x8*)(Brow + s * 16 * Cch + k0);
            acc[s] = __builtin_amdgcn_mfma_f32_16x16x32_f16(a, bb, acc[s], 0, 0, 0);
        }
    }
    if (!isV) {
        const int cch = (w << 1) + (quad >> 1);
        const int hof = (quad & 1) * 4;
        #pragma unroll
        for (int s = 0; s < 8; ++s) {
            int ng = n0 + s * 16 + tx;
            f16x4 pk;
            pk[0] = (_Float16)acc[s][0]; pk[1] = (_Float16)acc[s][1];
            pk[2] = (_Float16)acc[s][2]; pk[3] = (_Float16)acc[s][3];
            int rK = ng & 63, jt = ng >> 6;
            size_t ka = ((size_t)((b * Hh + (o0 >> 6)) * 32 + jt) << 12)
                      + rK * 64 + ((cch ^ (rK & 7)) * 8) + hof;
            *(f16x4*)&Kt[ka] = pk;
            int iQ = ((ng & 511) << 2) + (o0 >> 6);
            int rQ = iQ & 63, it = iQ >> 6;
            size_t qa = ((size_t)((b * Hh + (ng >> 9)) * 32 + it) << 12)
                      + rQ * 64 + ((cch ^ (rQ & 7)) * 8) + hof;
            *(f16x4*)&Qg[qa] = pk;
        }
        return;
    }
    float bv[4];
    {
        int ob = o0 + w * 16 + quad * 4;
        bv[0] = vbias[ob]; bv[1] = vbias[ob + 1]; bv[2] = vbias[ob + 2]; bv[3] = vbias[ob + 3];
    }
    #pragma unroll
    for (int s = 0; s < 8; ++s) {
        int ol = w * 16 + quad * 4, nl = s * 16 + tx;
        EpB[ol + 0][nl] = (_Float16)(acc[s][0] + bv[0]);
        EpB[ol + 1][nl] = (_Float16)(acc[s][1] + bv[1]);
        EpB[ol + 2][nl] = (_Float16)(acc[s][2] + bv[2]);
        EpB[ol + 3][nl] = (_Float16)(acc[s][3] + bv[3]);
    }
    __syncthreads();
    int row = tid >> 2;
    const int m = tid & 3;
    const int pbase = (m >> 1) * 32 + (m & 1) * 4;
    const int seg = m * 16;
    #pragma unroll
    for (int half = 0; half < 2; ++half) {
        _Float16* yp = Vb + ((size_t)(b * Cch + o0 + row) * Npt) + n0 + half * 64 + pbase;
        #pragma unroll
        for (int g = 0; g < 4; ++g)
            *(f16x4*)(yp + g * 8) = *(f16x4*)&EpB[row][half * 64 + seg + g * 4];
    }
}

// ---------------- attention pass A: 128 i-rows/block (R8 shape — R9's 256-row widening
// reverted: occupancy drop 3->2 waves/SIMD cancelled the K-load amortization).
// Register-resident K, no LDS/barriers. Grid 1024, XCD-aware remap.
__global__ __launch_bounds__(256, 3) void k_attn_A(const _Float16* __restrict__ Qg,
        const _Float16* __restrict__ Kt, float* __restrict__ mP, float* __restrict__ lP) {
    const int flat = blockIdx.x;
    const int bh = (flat & 7) * 2 + ((flat >> 3) & 1);
    const int rest = flat >> 4;              // 0..63
    const int i0 = (rest & 15) * 128;
    const int jc = rest >> 4;                // 0..3
    const int tid = threadIdx.x, w = tid >> 6, q = (tid >> 4) & 3, tx = tid & 15;
    const int sx = tx & 7;
    f16x8 qa[2][2];
    #pragma unroll
    for (int g = 0; g < 2; ++g) {
        const _Float16* Qtile = Qg + ((size_t)(bh * 32 + ((i0 + g * 64) >> 6)) << 12);
        int r = w * 16 + tx;
        qa[g][0] = *(const f16x8*)(Qtile + r * 64 + (q ^ sx) * 8);
        qa[g][1] = *(const f16x8*)(Qtile + r * 64 + ((q + 4) ^ sx) * 8);
    }
    const _Float16* Kbase = Kt + ((size_t)(bh * 32) << 12);
    const int jt0 = jc * 8;
    float m2[2][4], l[2][4];
    #pragma unroll
    for (int g = 0; g < 2; ++g)
        #pragma unroll
        for (int r = 0; r < 4; ++r) { m2[g][r] = -1e30f; l[g][r] = 0.f; }
    for (int t = 0; t < 8; ++t) {
        const _Float16* kpage = Kbase + ((size_t)(jt0 + t) << 12);
        f16x8 kb0[4], kb1[4];
        #pragma unroll
        for (int s = 0; s < 4; ++s) {
            int r = s * 16 + tx;
            kb0[s] = *(const f16x8*)(kpage + r * 64 + (q ^ sx) * 8);
            kb1[s] = *(const f16x8*)(kpage + r * 64 + ((q + 4) ^ sx) * 8);
        }
        #pragma unroll
        for (int g = 0; g < 2; ++g) {
            f32x4 e[4];
            __builtin_amdgcn_s_setprio(1);
            #pragma unroll
            for (int s = 0; s < 4; ++s) {
                f32x4 z = (f32x4){0.f, 0.f, 0.f, 0.f};
                z = __builtin_amdgcn_mfma_f32_16x16x32_f16(qa[g][0], kb0[s], z, 0, 0, 0);
                e[s] = __builtin_amdgcn_mfma_f32_16x16x32_f16(qa[g][1], kb1[s], z, 0, 0, 0);
            }
            __builtin_amdgcn_s_setprio(0);
            #pragma unroll
            for (int r = 0; r < 4; ++r) {
                float e0 = e[0][r] * L2E, e1 = e[1][r] * L2E;
                float e2 = e[2][r] * L2E, e3 = e[3][r] * L2E;
                float lm = fmaxf(fmaxf(e0, e1), fmaxf(e2, e3));
                float nm = fmaxf(m2[g][r], lm);
                l[g][r] = l[g][r] * fexp2(m2[g][r] - nm)
                        + fexp2(e0 - nm) + fexp2(e1 - nm) + fexp2(e2 - nm) + fexp2(e3 - nm);
                m2[g][r] = nm;
            }
        }
    }
    #pragma unroll
    for (int g = 0; g < 2; ++g)
        #pragma unroll
        for (int r = 0; r < 4; ++r) {
            float mm = m2[g][r], ll = l[g][r];
            #pragma unroll
            for (int off = 1; off < 16; off <<= 1) {
                float om = __shfl_xor(mm, off), ol = __shfl_xor(ll, off);
                float nm = fmaxf(mm, om);
                ll = ll * fexp2(mm - nm) + ol * fexp2(om - nm);
                mm = nm;
            }
            if (tx == 0) {
                int idx = bh * Npt + i0 + g * 64 + w * 16 + q * 4 + r;
                mP[jc * NROW + idx] = mm;
                lP[jc * NROW + idx] = ll;
            }
        }
}

// ---------------- attention pass B: traffic-minimal shape (256 thr / 4 waves, grid 512,
// wave = FULL j=64 x 512 i) + in-register PV (permuted Vb) + hoisted Q/V loads +
// setprio around PV. ~195 VGPR, fits (256,2)'s 256. Bit-identical output.
__global__ __launch_bounds__(256, 2) void k_attn_B(const _Float16* __restrict__ Qg,
        const _Float16* __restrict__ Kt, const _Float16* __restrict__ Vb,
        const float* __restrict__ mP, const float* __restrict__ lP,
        const float* __restrict__ h, _Float16* __restrict__ XT) {
    __shared__ float mlm[Npt];            // fused mlcomb: row max (base-2)
    __shared__ float mll[Npt];            // fused mlcomb: L2E / l
    __shared__ float Ssh[4][64];          // per-wave column-sum partials
    __shared__ _Float16 TS[4][4096];      // 32KB: per-wave [64 j][64 d] swizzled T-partial
    const int flat = blockIdx.x;
    const int bh = (flat & 7) * 2 + ((flat >> 3) & 1);
    const int j0 = (flat >> 4) * 64;
    const int b = bh >> 2, hd = bh & 3;
    const int tid = threadIdx.x, w = tid >> 6, q = (tid >> 4) & 3, tx = tid & 15;
    const int sx = tx & 7;
    // ---- fused mlcomb: combine 4 j-chunk (m,l) partials for this bh into LDS ----
    {
        const int ib = tid * 8;
        #pragma unroll
        for (int e = 0; e < 2; ++e) {
            int ii = ib + e * 4;
            int idx = bh * Npt + ii;
            float4 m0 = *(const float4*)&mP[idx];
            float4 m1 = *(const float4*)&mP[NROW + idx];
            float4 m2 = *(const float4*)&mP[2 * NROW + idx];
            float4 m3 = *(const float4*)&mP[3 * NROW + idx];
            float4 l0 = *(const float4*)&lP[idx];
            float4 l1 = *(const float4*)&lP[NROW + idx];
            float4 l2 = *(const float4*)&lP[2 * NROW + idx];
            float4 l3 = *(const float4*)&lP[3 * NROW + idx];
            #pragma unroll
            for (int k = 0; k < 4; ++k) {
                float a0 = ((const float*)&m0)[k], a1 = ((const float*)&m1)[k];
                float a2 = ((const float*)&m2)[k], a3 = ((const float*)&m3)[k];
                float mm = fmaxf(fmaxf(a0, a1), fmaxf(a2, a3));
                float ll = ((const float*)&l0)[k] * fexp2(a0 - mm)
                         + ((const float*)&l1)[k] * fexp2(a1 - mm)
                         + ((const float*)&l2)[k] * fexp2(a2 - mm)
                         + ((const float*)&l3)[k] * fexp2(a3 - mm);
                mlm[ii + k] = mm;
                mll[ii + k] = L2E / ll;
            }
        }
    }
    // ---- K fragments for the full 64-j tile (register-resident, 32 VGPR) ----
    f16x8 kb[4][2];
    {
        const _Float16* Ktile = Kt + ((size_t)(bh * 32 + (j0 >> 6)) << 12);
        #pragma unroll
        for (int nt = 0; nt < 4; ++nt) {
            int r = nt * 16 + tx;
            kb[nt][0] = *(const f16x8*)(Ktile + r * 64 + (q ^ sx) * 8);
            kb[nt][1] = *(const f16x8*)(Ktile + r * 64 + ((q + 4) ^ sx) * 8);
        }
    }
    __syncthreads();
    f32x4 Tacc[4][4];
    #pragma unroll
    for (int mt = 0; mt < 4; ++mt)
        #pragma unroll
        for (int nt = 0; nt < 4; ++nt) Tacc[mt][nt] = (f32x4){0.f, 0.f, 0.f, 0.f};
    float scS[4] = {0.f, 0.f, 0.f, 0.f};
    const _Float16* vbase = Vb + (size_t)(b * Cch + hd * 64) * Npt;
    for (int it = 0; it < 8; ++it) {
        const int i0 = w * 512 + it * 64;
        const _Float16* Qtile = Qg + ((size_t)(bh * 32 + (i0 >> 6)) << 12);
        // ---- issue ALL of this iteration's Q and V loads up front ----
        f16x8 qv[2][2][2];   // [pp][mt2][half]
        f16x8 vv[2][4];      // [pp][mtd]
        #pragma unroll
        for (int pp = 0; pp < 2; ++pp) {
            #pragma unroll
            for (int mt2 = 0; mt2 < 2; ++mt2) {
                const int r = (pp * 2 + mt2) * 16 + tx;
                qv[pp][mt2][0] = *(const f16x8*)(Qtile + r * 64 + (q ^ sx) * 8);
                qv[pp][mt2][1] = *(const f16x8*)(Qtile + r * 64 + ((q + 4) ^ sx) * 8);
            }
            #pragma unroll
            for (int mtd = 0; mtd < 4; ++mtd)
                vv[pp][mtd] = *(const f16x8*)(vbase + (size_t)(mtd * 16 + tx) * Npt + i0 + pp * 32 + q * 8);
        }
        #pragma unroll
        for (int pp = 0; pp < 2; ++pp) {
            f16x4 pk[2][4];
            #pragma unroll
            for (int mt2 = 0; mt2 < 2; ++mt2) {
                const int mt = pp * 2 + mt2;
                float4 m2v = *(const float4*)&mlm[i0 + mt * 16 + q * 4];
                float4 liv = *(const float4*)&mll[i0 + mt * 16 + q * 4];
                #pragma unroll
                for (int nt = 0; nt < 4; ++nt) {
                    f32x4 z = (f32x4){0.f, 0.f, 0.f, 0.f};
                    z = __builtin_amdgcn_mfma_f32_16x16x32_f16(qv[pp][mt2][0], kb[nt][0], z, 0, 0, 0);
                    z = __builtin_amdgcn_mfma_f32_16x16x32_f16(qv[pp][mt2][1], kb[nt][1], z, 0, 0, 0);
                    float a0 = fexp2(fexp2(__builtin_fmaf(z[0], L2E, -m2v.x)) * liv.x);
                    float a1 = fexp2(fexp2(__builtin_fmaf(z[1], L2E, -m2v.y)) * liv.y);
                    float a2 = fexp2(fexp2(__builtin_fmaf(z[2], L2E, -m2v.z)) * liv.z);
                    float a3 = fexp2(fexp2(__builtin_fmaf(z[3], L2E, -m2v.w)) * liv.w);
                    scS[nt] += a0 + a1 + a2 + a3;
                    f16x4 pkk;
                    pkk[0] = (_Float16)a0; pkk[1] = (_Float16)a1;
                    pkk[2] = (_Float16)a2; pkk[3] = (_Float16)a3;
                    pk[mt2][nt] = pkk;
                }
            }
            __builtin_amdgcn_s_setprio(1);
            #pragma unroll
            for (int mtd = 0; mtd < 4; ++mtd) {
                #pragma unroll
                for (int nt = 0; nt < 4; ++nt) {
                    f16x8 pb = __builtin_shufflevector(pk[0][nt], pk[1][nt], 0, 1, 2, 3, 4, 5, 6, 7);
                    Tacc[mtd][nt] = __builtin_amdgcn_mfma_f32_16x16x32_f16(vv[pp][mtd], pb, Tacc[mtd][nt], 0, 0, 0);
                }
            }
            __builtin_amdgcn_s_setprio(0);
        }
    }
    // ---- column-sum partials (wave's 512 i-rows, 64 j) ----
    #pragma unroll
    for (int nt = 0; nt < 4; ++nt) {
        float s = scS[nt];
        s += __shfl_xor(s, 16);
        s += __shfl_xor(s, 32);
        if (q == 0) Ssh[w][nt * 16 + tx] = s;
    }
    // ---- per-wave T partial into TS[w], swizzled [64 j][64 d] ----
    #pragma unroll
    for (int mtd = 0; mtd < 4; ++mtd)
        #pragma unroll
        for (int nt = 0; nt < 4; ++nt) {
            f16x4 pkk;
            pkk[0] = (_Float16)Tacc[mtd][nt][0];
            pkk[1] = (_Float16)Tacc[mtd][nt][1];
            pkk[2] = (_Float16)Tacc[mtd][nt][2];
            pkk[3] = (_Float16)Tacc[mtd][nt][3];
            *(f16x4*)&TS[w][(nt * 16 + tx) * 64 + ((2 * mtd + (q >> 1)) ^ sx) * 8 + (q & 1) * 4] = pkk;
        }
    __syncthreads();
    // ---- reduce 4 i-chunk partials; u = h - T/S; direct XT write (2 slices/thread) ----
    {
        const int jl = tid >> 2, d4 = tid & 3;
        const float s4 = Ssh[0][jl] + Ssh[1][jl] + Ssh[2][jl] + Ssh[3][jl];
        const float rs = 1.f / s4;
        const int jg = j0 + jl;
        #pragma unroll
        for (int g = 0; g < 2; ++g) {
            const int s8 = d4 * 2 + g;
            const int base = jl * 64 + ((s8 ^ (jl & 7)) * 8);
            f16x8 t0 = *(const f16x8*)&TS[0][base];
            f16x8 t1 = *(const f16x8*)&TS[1][base];
            f16x8 t2 = *(const f16x8*)&TS[2][base];
            f16x8 t3 = *(const f16x8*)&TS[3][base];
            const float* hp = h + ((size_t)(b * Cch + hd * 64 + s8 * 8) * Npt) + jg;
            f16x8 u;
            #pragma unroll
            for (int e = 0; e < 8; ++e) {
                float tv = (float)t0[e] + (float)t1[e] + (float)t2[e] + (float)t3[e];
                u[e] = (_Float16)(hp[(size_t)e * Npt] - tv * rs);
            }
            *(f16x8*)(XT + ((size_t)(b * Npt + jg) * Cch) + hd * 64 + s8 * 8) = u;
        }
    }
}

extern "C" void kernel_launch(void* const* d_in, const int* in_sizes, int n_in,
                              void* d_out, int out_size, void* d_ws, size_t ws_size,
                              hipStream_t stream) {
    (void)in_sizes; (void)n_in; (void)out_size; (void)ws_size;
    const float* x    = (const float*)d_in[0];
    const float* xyz  = (const float*)d_in[1];
    const float* c1w  = (const float*)d_in[2];
    const float* posw = (const float*)d_in[3];
    const float* posb = (const float*)d_in[4];
    const float* bn1g = (const float*)d_in[5];
    const float* bn1b = (const float*)d_in[6];
    const float* qkw  = (const float*)d_in[7];
    const float* vw   = (const float*)d_in[8];
    const float* vb   = (const float*)d_in[9];
    const float* tw   = (const float*)d_in[10];
    const float* tb   = (const float*)d_in[11];
    const float* bng  = (const float*)d_in[12];
    const float* bnb  = (const float*)d_in[13];
    float* out = (float*)d_out;

    const size_t NE = (size_t)Bsz * Cch * Npt;   // 2,097,152
    char* W = (char*)d_ws;
    float* emb   = (float*)W;                 W += NE * 4;
    float* h     = (float*)W;                 W += NE * 4;
    _Float16* XT = (_Float16*)W;              W += NE * 2;
    _Float16* Qg = (_Float16*)W;              W += NE * 2;
    _Float16* Kt = (_Float16*)W;              W += NE * 2;
    _Float16* Vb = (_Float16*)W;              W += NE * 2;
    _Float16* wbf = (_Float16*)W;             W += 851968 * 2;
    float* mP    = (float*)W;                 W += 4 * NROW * 4;
    float* lP    = (float*)W;                 W += 4 * NROW * 4;
    float* bnacc = (float*)W;                 W += 5 * 512 * 4;   // 5 slots x (sum,sum2)
    unsigned* cnt = (unsigned*)W;             W += 5 * 4;         // 5 barrier counters

    dim3 blk(256);
    dim3 g4(Npt / 64, Cch / 64, Bsz);    // 32,4,4 = 512 blocks (== GB_BLOCKS)
    dim3 gQKV(Npt / 128, 8, Bsz);        // 16,8,4 — fused qk+v, 128-wide n tiles
    int ew = (int)(NE / 256);

    k_init<<<ew, blk, 0, stream>>>(xyz, posw, posb, emb, c1w, qkw, vw, tw, wbf, bnacc, cnt);

    // h0 = relu(bn1(conv1_w @ x)); XT = transpose(h0 + emb)
    k_fuse_t<<<g4, blk, 0, stream>>>(x, XT);
    k_gemm_bn<<<g4, blk, 0, stream>>>(wbf, XT, nullptr, bnacc, cnt + 0,
                                      bn1g, bn1b, emb, nullptr, h, nullptr, XT, 0);

    for (int L = 0; L < NL; ++L) {
        const _Float16* qkL = wbf + 65536 + (size_t)L * 65536;
        const _Float16* vL  = wbf + 327680 + (size_t)L * 65536;
        const _Float16* tL  = wbf + 589824 + (size_t)L * 65536;
        float* accL = bnacc + (1 + L) * 512;
        k_gemm_qkv<<<gQKV, blk, 0, stream>>>(qkL, vL, XT, vb + L * Cch, Vb, Qg, Kt);
        k_attn_A<<<1024, blk, 0, stream>>>(Qg, Kt, mP, lP);
        k_attn_B<<<512, blk, 0, stream>>>(Qg, Kt, Vb, mP, lP, h, XT);
        k_gemm_bn<<<g4, blk, 0, stream>>>(tL, XT, tb + L * Cch, accL, cnt + 1 + L,
                                          bng + L * Cch, bnb + L * Cch, emb, h, h, out, XT, L);
    }
}

// Round 12
// 654.231 us; speedup vs baseline: 1.0208x; 1.0208x over previous
//
#include <hip/hip_runtime.h>
#include <math.h>

#define Bsz 4
#define Cch 256
#define Npt 2048
#define Hh  4
#define NL  4
#define BN_CNT (Bsz * Npt)   // 8192
#define EPSV 1e-5f
#define NROW (16 * Npt)      // 32768 attention rows total (bh * Npt)
#define L2E 1.44269504f
#define GB_BLOCKS 512u       // k_gemm_bn grid size (must equal g4 product)

typedef _Float16 f16x8 __attribute__((ext_vector_type(8)));
typedef _Float16 f16x4 __attribute__((ext_vector_type(4)));
typedef float    f32x4 __attribute__((ext_vector_type(4)));

__device__ __forceinline__ float fexp2(float x) { return __builtin_amdgcn_exp2f(x); }

// ---------------- init: xyz embedding + weight cast + bnacc/cnt zero (merged) ----------------
__global__ void k_init(const float* __restrict__ xyz, const float* __restrict__ pw,
                       const float* __restrict__ pb, float* __restrict__ emb,
                       const float* __restrict__ c1w, const float* __restrict__ qkw,
                       const float* __restrict__ vw, const float* __restrict__ tw,
                       _Float16* __restrict__ o, float* __restrict__ bnacc,
                       unsigned* __restrict__ cnt) {
    int idx = blockIdx.x * 256 + threadIdx.x;   // 0 .. NE-1 (2,097,152)
    int n = idx & (Npt - 1);
    int c = (idx >> 11) & (Cch - 1);
    int b = idx >> 19;
    const float* xz = xyz + (b * Npt + n) * 3;
    emb[idx] = pw[c * 3 + 0] * xz[0] + pw[c * 3 + 1] * xz[1] + pw[c * 3 + 2] * xz[2] + pb[c];
    if (idx < 5 * 512) bnacc[idx] = 0.f;     // 5 slots x (sum[256], sum2[256])
    if (idx < 5) cnt[idx] = 0u;              // 5 barrier counters (one per gemm_bn call)
    if (idx < 851968) {
        const float* src; int off;
        if (idx < 65536)         { src = c1w; off = idx; }
        else if (idx < 327680)   { src = qkw; off = idx - 65536; }
        else if (idx < 589824)   { src = vw;  off = idx - 327680; }
        else                     { src = tw;  off = idx - 589824; }
        o[idx] = (_Float16)src[off];
    }
}

// ---------------- transpose + cast x -> XT[b][n][c] (entry only) ----------------
__global__ __launch_bounds__(256) void k_fuse_t(const float* __restrict__ in,
        _Float16* __restrict__ XT) {
    __shared__ _Float16 Tt[64][72];
    const int b = blockIdx.z, c0 = blockIdx.y * 64, n0 = blockIdx.x * 64;
    const int t = threadIdx.x;
    const int cl = t >> 2, ns = (t & 3) * 16;
    const float* ip = in + ((size_t)(b * Cch + c0 + cl) * Npt) + n0 + ns;
    #pragma unroll
    for (int g = 0; g < 4; ++g) {
        float4 v = *(const float4*)(ip + g * 4);
        Tt[ns + g * 4 + 0][cl] = (_Float16)v.x;
        Tt[ns + g * 4 + 1][cl] = (_Float16)v.y;
        Tt[ns + g * 4 + 2][cl] = (_Float16)v.z;
        Tt[ns + g * 4 + 3][cl] = (_Float16)v.w;
    }
    __syncthreads();
    int nl = t >> 2, cs = (t & 3) * 16;
    _Float16* op = XT + ((size_t)(b * Npt + n0 + nl) * Cch) + c0 + cs;
    #pragma unroll
    for (int g = 0; g < 4; ++g)
        *(f16x4*)(op + g * 4) = *(f16x4*)&Tt[nl][cs + g * 4];
}

// ---------------- FUSED MFMA GEMM + BN + relu + residual + out + transpose -> XT ----------------
// R10 post-mortem: the barrier's per-iteration agent-scope ACQUIRE load emitted an L1
// invalidate every poll, poisoning the co-resident block's L1 while it was still in its
// GEMM (MfmaUtil 0.58%, dur 65us). Fix: RELAXED spin (glc read, no invalidate; coherent
// for cnt since it bypasses L1) + s_sleep(16) backoff + ONE __threadfence() after exit
// (R11's __hip_atomic_fence builtin doesn't exist on this toolchain). All cross-block
// data (cnt, bnacc) is read via agent-scope atomic loads that bypass L1, so the single
// fence is ordering-only. Deadlock-safe: grid 512, VGPR 40, LDS 26.6KB -> co-resident.
__global__ __launch_bounds__(256, 2) void k_gemm_bn(const _Float16* __restrict__ Wb,
        const _Float16* __restrict__ XT, const float* __restrict__ bias,
        float* __restrict__ bnacc, unsigned* __restrict__ cnt,
        const float* __restrict__ g, const float* __restrict__ bt,
        const float* __restrict__ emb, const float* __restrict__ resid,
        float* __restrict__ hout, float* __restrict__ out, _Float16* __restrict__ XTo,
        int layer) {
    __shared__ float EpF[64][68];
    __shared__ _Float16 Tt[64][72];
    const int b = blockIdx.z, o0 = blockIdx.y * 64, n0 = blockIdx.x * 64;
    const int tid = threadIdx.x, w = tid >> 6, quad = (tid >> 4) & 3, tx = tid & 15;
    const _Float16* Arow = Wb + (o0 + w * 16 + tx) * Cch + quad * 8;
    const _Float16* Brow = XT + ((size_t)(b * Npt + n0 + tx) * Cch) + quad * 8;
    f32x4 acc[4];
    #pragma unroll
    for (int s = 0; s < 4; ++s) acc[s] = (f32x4){0.f, 0.f, 0.f, 0.f};
    for (int k0 = 0; k0 < Cch; k0 += 32) {
        f16x8 a = *(const f16x8*)(Arow + k0);
        #pragma unroll
        for (int s = 0; s < 4; ++s) {
            f16x8 bb = *(const f16x8*)(Brow + s * 16 * Cch + k0);
            acc[s] = __builtin_amdgcn_mfma_f32_16x16x32_f16(a, bb, acc[s], 0, 0, 0);
        }
    }
    float bv[4];
    {
        int ob = o0 + w * 16 + quad * 4;
        if (bias) { bv[0] = bias[ob]; bv[1] = bias[ob + 1]; bv[2] = bias[ob + 2]; bv[3] = bias[ob + 3]; }
        else bv[0] = bv[1] = bv[2] = bv[3] = 0.f;
    }
    #pragma unroll
    for (int s = 0; s < 4; ++s) {
        int ol = w * 16 + quad * 4, nl = s * 16 + tx;
        EpF[ol + 0][nl] = acc[s][0] + bv[0];
        EpF[ol + 1][nl] = acc[s][1] + bv[1];
        EpF[ol + 2][nl] = acc[s][2] + bv[2];
        EpF[ol + 3][nl] = acc[s][3] + bv[3];
    }
    __syncthreads();
    // ---- BN partial stats from EpF (identical math/order to the split version) ----
    {
        int row = tid >> 2, seg = (tid & 3) * 16;
        float s1 = 0.f, s2 = 0.f;
        #pragma unroll
        for (int gi = 0; gi < 4; ++gi) {
            float4 v = *(float4*)&EpF[row][seg + gi * 4];
            s1 += v.x + v.y + v.z + v.w;
            s2 += v.x * v.x + v.y * v.y + v.z * v.z + v.w * v.w;
        }
        s1 += __shfl_xor(s1, 1); s2 += __shfl_xor(s2, 1);
        s1 += __shfl_xor(s1, 2); s2 += __shfl_xor(s2, 2);
        if ((tid & 3) == 0) {
            atomicAdd(&bnacc[o0 + row], s1);
            atomicAdd(&bnacc[256 + o0 + row], s2);
        }
    }
    // ---- device-wide barrier: relaxed spin + backoff, single fence on exit ----
    __syncthreads();                       // drains this block's atomics before arrival
    if (tid == 0) {
        __threadfence();
        atomicAdd(cnt, 1u);
        while (__hip_atomic_load(cnt, __ATOMIC_RELAXED, __HIP_MEMORY_SCOPE_AGENT) < GB_BLOCKS)
            __builtin_amdgcn_s_sleep(16);
        __threadfence();
    }
    __syncthreads();
    // ---- BN epilogue from LDS tile ----
    const int cl = tid >> 2, ns = (tid & 3) * 16;
    const int c = o0 + cl;
    const float smn = __hip_atomic_load(&bnacc[c], __ATOMIC_RELAXED, __HIP_MEMORY_SCOPE_AGENT);
    const float sv2 = __hip_atomic_load(&bnacc[256 + c], __ATOMIC_RELAXED, __HIP_MEMORY_SCOPE_AGENT);
    const float mn = smn * (1.f / BN_CNT);
    const float var = sv2 * (1.f / BN_CNT) - mn * mn;
    const float is = rsqrtf(var + EPSV);
    const float gg = g[c], bb = bt[c];
    const size_t rowoff = ((size_t)(b * Cch + c) * Npt) + n0 + ns;
    const float* ep = emb + rowoff;
    const float* rp = resid ? resid + rowoff : nullptr;
    float* hp = hout + rowoff;
    float* op = out ? out + (size_t)b * (NL * Cch * Npt) + (size_t)(layer * Cch + c) * Npt + n0 + ns
                    : nullptr;
    #pragma unroll
    for (int gi = 0; gi < 4; ++gi) {
        float4 v = *(const float4*)&EpF[cl][ns + gi * 4];
        float4 y;
        y.x = fmaxf(gg * (v.x - mn) * is + bb, 0.f);
        y.y = fmaxf(gg * (v.y - mn) * is + bb, 0.f);
        y.z = fmaxf(gg * (v.z - mn) * is + bb, 0.f);
        y.w = fmaxf(gg * (v.w - mn) * is + bb, 0.f);
        if (rp) {
            float4 r = *(const float4*)(rp + gi * 4);
            y.x += r.x; y.y += r.y; y.z += r.z; y.w += r.w;
        }
        *(float4*)(hp + gi * 4) = y;
        if (op) *(float4*)(op + gi * 4) = y;
        float4 e = *(const float4*)(ep + gi * 4);
        Tt[ns + gi * 4 + 0][cl] = (_Float16)(y.x + e.x);
        Tt[ns + gi * 4 + 1][cl] = (_Float16)(y.y + e.y);
        Tt[ns + gi * 4 + 2][cl] = (_Float16)(y.z + e.z);
        Tt[ns + gi * 4 + 3][cl] = (_Float16)(y.w + e.w);
    }
    __syncthreads();
    int nl = tid >> 2, cs = (tid & 3) * 16;
    _Float16* xp = XTo + ((size_t)(b * Npt + n0 + nl) * Cch) + o0 + cs;
    #pragma unroll
    for (int gi = 0; gi < 4; ++gi)
        *(f16x4*)(xp + gi * 4) = *(f16x4*)&Tt[nl][cs + gi * 4];
}

// ---------------- fused qk + v GEMM, 64o x 128n tiles: y<4 -> Qg/Kt (swizzled),
// y>=4 -> Vb fp16 (permuted columns). Grid (16,8,4)=512, 2 blocks/CU.
__global__ __launch_bounds__(256) void k_gemm_qkv(const _Float16* __restrict__ Wqk,
        const _Float16* __restrict__ Wv, const _Float16* __restrict__ XT,
        const float* __restrict__ vbias, _Float16* __restrict__ Vb,
        _Float16* __restrict__ Qg, _Float16* __restrict__ Kt) {
    __shared__ _Float16 EpB[64][136];
    const int b = blockIdx.z, y = blockIdx.y, n0 = blockIdx.x * 128;
    const int isV = (y >= 4);
    const int o0 = (isV ? (y - 4) : y) * 64;
    const _Float16* Wb = isV ? Wv : Wqk;
    const int tid = threadIdx.x, w = tid >> 6, quad = (tid >> 4) & 3, tx = tid & 15;
    const _Float16* Arow = Wb + (o0 + w * 16 + tx) * Cch + quad * 8;
    const _Float16* Brow = XT + ((size_t)(b * Npt + n0 + tx) * Cch) + quad * 8;
    f32x4 acc[8];
    #pragma unroll
    for (int s = 0; s < 8; ++s) acc[s] = (f32x4){0.f, 0.f, 0.f, 0.f};
    for (int k0 = 0; k0 < Cch; k0 += 32) {
        f16x8 a = *(const f16x8*)(Arow + k0);
        #pragma unroll
        for (int s = 0; s < 8; ++s) {
            f16x8 bb = *(const f16x8*)(Brow + s * 16 * Cch + k0);
            acc[s] = __builtin_amdgcn_mfma_f32_16x16x32_f16(a, bb, acc[s], 0, 0, 0);
        }
    }
    if (!isV) {
        const int cch = (w << 1) + (quad >> 1);
        const int hof = (quad & 1) * 4;
        #pragma unroll
        for (int s = 0; s < 8; ++s) {
            int ng = n0 + s * 16 + tx;
            f16x4 pk;
            pk[0] = (_Float16)acc[s][0]; pk[1] = (_Float16)acc[s][1];
            pk[2] = (_Float16)acc[s][2]; pk[3] = (_Float16)acc[s][3];
            int rK = ng & 63, jt = ng >> 6;
            size_t ka = ((size_t)((b * Hh + (o0 >> 6)) * 32 + jt) << 12)
                      + rK * 64 + ((cch ^ (rK & 7)) * 8) + hof;
            *(f16x4*)&Kt[ka] = pk;
            int iQ = ((ng & 511) << 2) + (o0 >> 6);
            int rQ = iQ & 63, it = iQ >> 6;
            size_t qa = ((size_t)((b * Hh + (ng >> 9)) * 32 + it) << 12)
                      + rQ * 64 + ((cch ^ (rQ & 7)) * 8) + hof;
            *(f16x4*)&Qg[qa] = pk;
        }
        return;
    }
    float bv[4];
    {
        int ob = o0 + w * 16 + quad * 4;
        bv[0] = vbias[ob]; bv[1] = vbias[ob + 1]; bv[2] = vbias[ob + 2]; bv[3] = vbias[ob + 3];
    }
    #pragma unroll
    for (int s = 0; s < 8; ++s) {
        int ol = w * 16 + quad * 4, nl = s * 16 + tx;
        EpB[ol + 0][nl] = (_Float16)(acc[s][0] + bv[0]);
        EpB[ol + 1][nl] = (_Float16)(acc[s][1] + bv[1]);
        EpB[ol + 2][nl] = (_Float16)(acc[s][2] + bv[2]);
        EpB[ol + 3][nl] = (_Float16)(acc[s][3] + bv[3]);
    }
    __syncthreads();
    int row = tid >> 2;
    const int m = tid & 3;
    const int pbase = (m >> 1) * 32 + (m & 1) * 4;
    const int seg = m * 16;
    #pragma unroll
    for (int half = 0; half < 2; ++half) {
        _Float16* yp = Vb + ((size_t)(b * Cch + o0 + row) * Npt) + n0 + half * 64 + pbase;
        #pragma unroll
        for (int g = 0; g < 4; ++g)
            *(f16x4*)(yp + g * 8) = *(f16x4*)&EpB[row][half * 64 + seg + g * 4];
    }
}

// ---------------- attention pass A: 128 i-rows/block, register-resident K, no LDS,
// no barriers. Grid 1024, XCD-aware remap.
__global__ __launch_bounds__(256, 3) void k_attn_A(const _Float16* __restrict__ Qg,
        const _Float16* __restrict__ Kt, float* __restrict__ mP, float* __restrict__ lP) {
    const int flat = blockIdx.x;
    const int bh = (flat & 7) * 2 + ((flat >> 3) & 1);
    const int rest = flat >> 4;              // 0..63
    const int i0 = (rest & 15) * 128;
    const int jc = rest >> 4;                // 0..3
    const int tid = threadIdx.x, w = tid >> 6, q = (tid >> 4) & 3, tx = tid & 15;
    const int sx = tx & 7;
    f16x8 qa[2][2];
    #pragma unroll
    for (int g = 0; g < 2; ++g) {
        const _Float16* Qtile = Qg + ((size_t)(bh * 32 + ((i0 + g * 64) >> 6)) << 12);
        int r = w * 16 + tx;
        qa[g][0] = *(const f16x8*)(Qtile + r * 64 + (q ^ sx) * 8);
        qa[g][1] = *(const f16x8*)(Qtile + r * 64 + ((q + 4) ^ sx) * 8);
    }
    const _Float16* Kbase = Kt + ((size_t)(bh * 32) << 12);
    const int jt0 = jc * 8;
    float m2[2][4], l[2][4];
    #pragma unroll
    for (int g = 0; g < 2; ++g)
        #pragma unroll
        for (int r = 0; r < 4; ++r) { m2[g][r] = -1e30f; l[g][r] = 0.f; }
    for (int t = 0; t < 8; ++t) {
        const _Float16* kpage = Kbase + ((size_t)(jt0 + t) << 12);
        f16x8 kb0[4], kb1[4];
        #pragma unroll
        for (int s = 0; s < 4; ++s) {
            int r = s * 16 + tx;
            kb0[s] = *(const f16x8*)(kpage + r * 64 + (q ^ sx) * 8);
            kb1[s] = *(const f16x8*)(kpage + r * 64 + ((q + 4) ^ sx) * 8);
        }
        #pragma unroll
        for (int g = 0; g < 2; ++g) {
            f32x4 e[4];
            __builtin_amdgcn_s_setprio(1);
            #pragma unroll
            for (int s = 0; s < 4; ++s) {
                f32x4 z = (f32x4){0.f, 0.f, 0.f, 0.f};
                z = __builtin_amdgcn_mfma_f32_16x16x32_f16(qa[g][0], kb0[s], z, 0, 0, 0);
                e[s] = __builtin_amdgcn_mfma_f32_16x16x32_f16(qa[g][1], kb1[s], z, 0, 0, 0);
            }
            __builtin_amdgcn_s_setprio(0);
            #pragma unroll
            for (int r = 0; r < 4; ++r) {
                float e0 = e[0][r] * L2E, e1 = e[1][r] * L2E;
                float e2 = e[2][r] * L2E, e3 = e[3][r] * L2E;
                float lm = fmaxf(fmaxf(e0, e1), fmaxf(e2, e3));
                float nm = fmaxf(m2[g][r], lm);
                l[g][r] = l[g][r] * fexp2(m2[g][r] - nm)
                        + fexp2(e0 - nm) + fexp2(e1 - nm) + fexp2(e2 - nm) + fexp2(e3 - nm);
                m2[g][r] = nm;
            }
        }
    }
    #pragma unroll
    for (int g = 0; g < 2; ++g)
        #pragma unroll
        for (int r = 0; r < 4; ++r) {
            float mm = m2[g][r], ll = l[g][r];
            #pragma unroll
            for (int off = 1; off < 16; off <<= 1) {
                float om = __shfl_xor(mm, off), ol = __shfl_xor(ll, off);
                float nm = fmaxf(mm, om);
                ll = ll * fexp2(mm - nm) + ol * fexp2(om - nm);
                mm = nm;
            }
            if (tx == 0) {
                int idx = bh * Npt + i0 + g * 64 + w * 16 + q * 4 + r;
                mP[jc * NROW + idx] = mm;
                lP[jc * NROW + idx] = ll;
            }
        }
}

// ---------------- attention pass B: traffic-minimal shape (256 thr / 4 waves, grid 512,
// wave = FULL j=64 x 512 i) + in-register PV (permuted Vb) + hoisted Q/V loads +
// setprio around PV. ~195 VGPR, fits (256,2)'s 256. Bit-identical output.
__global__ __launch_bounds__(256, 2) void k_attn_B(const _Float16* __restrict__ Qg,
        const _Float16* __restrict__ Kt, const _Float16* __restrict__ Vb,
        const float* __restrict__ mP, const float* __restrict__ lP,
        const float* __restrict__ h, _Float16* __restrict__ XT) {
    __shared__ float mlm[Npt];            // fused mlcomb: row max (base-2)
    __shared__ float mll[Npt];            // fused mlcomb: L2E / l
    __shared__ float Ssh[4][64];          // per-wave column-sum partials
    __shared__ _Float16 TS[4][4096];      // 32KB: per-wave [64 j][64 d] swizzled T-partial
    const int flat = blockIdx.x;
    const int bh = (flat & 7) * 2 + ((flat >> 3) & 1);
    const int j0 = (flat >> 4) * 64;
    const int b = bh >> 2, hd = bh & 3;
    const int tid = threadIdx.x, w = tid >> 6, q = (tid >> 4) & 3, tx = tid & 15;
    const int sx = tx & 7;
    // ---- fused mlcomb: combine 4 j-chunk (m,l) partials for this bh into LDS ----
    {
        const int ib = tid * 8;
        #pragma unroll
        for (int e = 0; e < 2; ++e) {
            int ii = ib + e * 4;
            int idx = bh * Npt + ii;
            float4 m0 = *(const float4*)&mP[idx];
            float4 m1 = *(const float4*)&mP[NROW + idx];
            float4 m2 = *(const float4*)&mP[2 * NROW + idx];
            float4 m3 = *(const float4*)&mP[3 * NROW + idx];
            float4 l0 = *(const float4*)&lP[idx];
            float4 l1 = *(const float4*)&lP[NROW + idx];
            float4 l2 = *(const float4*)&lP[2 * NROW + idx];
            float4 l3 = *(const float4*)&lP[3 * NROW + idx];
            #pragma unroll
            for (int k = 0; k < 4; ++k) {
                float a0 = ((const float*)&m0)[k], a1 = ((const float*)&m1)[k];
                float a2 = ((const float*)&m2)[k], a3 = ((const float*)&m3)[k];
                float mm = fmaxf(fmaxf(a0, a1), fmaxf(a2, a3));
                float ll = ((const float*)&l0)[k] * fexp2(a0 - mm)
                         + ((const float*)&l1)[k] * fexp2(a1 - mm)
                         + ((const float*)&l2)[k] * fexp2(a2 - mm)
                         + ((const float*)&l3)[k] * fexp2(a3 - mm);
                mlm[ii + k] = mm;
                mll[ii + k] = L2E / ll;
            }
        }
    }
    // ---- K fragments for the full 64-j tile (register-resident, 32 VGPR) ----
    f16x8 kb[4][2];
    {
        const _Float16* Ktile = Kt + ((size_t)(bh * 32 + (j0 >> 6)) << 12);
        #pragma unroll
        for (int nt = 0; nt < 4; ++nt) {
            int r = nt * 16 + tx;
            kb[nt][0] = *(const f16x8*)(Ktile + r * 64 + (q ^ sx) * 8);
            kb[nt][1] = *(const f16x8*)(Ktile + r * 64 + ((q + 4) ^ sx) * 8);
        }
    }
    __syncthreads();
    f32x4 Tacc[4][4];
    #pragma unroll
    for (int mt = 0; mt < 4; ++mt)
        #pragma unroll
        for (int nt = 0; nt < 4; ++nt) Tacc[mt][nt] = (f32x4){0.f, 0.f, 0.f, 0.f};
    float scS[4] = {0.f, 0.f, 0.f, 0.f};
    const _Float16* vbase = Vb + (size_t)(b * Cch + hd * 64) * Npt;
    for (int it = 0; it < 8; ++it) {
        const int i0 = w * 512 + it * 64;
        const _Float16* Qtile = Qg + ((size_t)(bh * 32 + (i0 >> 6)) << 12);
        // ---- issue ALL of this iteration's Q and V loads up front ----
        f16x8 qv[2][2][2];   // [pp][mt2][half]
        f16x8 vv[2][4];      // [pp][mtd]
        #pragma unroll
        for (int pp = 0; pp < 2; ++pp) {
            #pragma unroll
            for (int mt2 = 0; mt2 < 2; ++mt2) {
                const int r = (pp * 2 + mt2) * 16 + tx;
                qv[pp][mt2][0] = *(const f16x8*)(Qtile + r * 64 + (q ^ sx) * 8);
                qv[pp][mt2][1] = *(const f16x8*)(Qtile + r * 64 + ((q + 4) ^ sx) * 8);
            }
            #pragma unroll
            for (int mtd = 0; mtd < 4; ++mtd)
                vv[pp][mtd] = *(const f16x8*)(vbase + (size_t)(mtd * 16 + tx) * Npt + i0 + pp * 32 + q * 8);
        }
        #pragma unroll
        for (int pp = 0; pp < 2; ++pp) {
            f16x4 pk[2][4];
            #pragma unroll
            for (int mt2 = 0; mt2 < 2; ++mt2) {
                const int mt = pp * 2 + mt2;
                float4 m2v = *(const float4*)&mlm[i0 + mt * 16 + q * 4];
                float4 liv = *(const float4*)&mll[i0 + mt * 16 + q * 4];
                #pragma unroll
                for (int nt = 0; nt < 4; ++nt) {
                    f32x4 z = (f32x4){0.f, 0.f, 0.f, 0.f};
                    z = __builtin_amdgcn_mfma_f32_16x16x32_f16(qv[pp][mt2][0], kb[nt][0], z, 0, 0, 0);
                    z = __builtin_amdgcn_mfma_f32_16x16x32_f16(qv[pp][mt2][1], kb[nt][1], z, 0, 0, 0);
                    float a0 = fexp2(fexp2(__builtin_fmaf(z[0], L2E, -m2v.x)) * liv.x);
                    float a1 = fexp2(fexp2(__builtin_fmaf(z[1], L2E, -m2v.y)) * liv.y);
                    float a2 = fexp2(fexp2(__builtin_fmaf(z[2], L2E, -m2v.z)) * liv.z);
                    float a3 = fexp2(fexp2(__builtin_fmaf(z[3], L2E, -m2v.w)) * liv.w);
                    scS[nt] += a0 + a1 + a2 + a3;
                    f16x4 pkk;
                    pkk[0] = (_Float16)a0; pkk[1] = (_Float16)a1;
                    pkk[2] = (_Float16)a2; pkk[3] = (_Float16)a3;
                    pk[mt2][nt] = pkk;
                }
            }
            __builtin_amdgcn_s_setprio(1);
            #pragma unroll
            for (int mtd = 0; mtd < 4; ++mtd) {
                #pragma unroll
                for (int nt = 0; nt < 4; ++nt) {
                    f16x8 pb = __builtin_shufflevector(pk[0][nt], pk[1][nt], 0, 1, 2, 3, 4, 5, 6, 7);
                    Tacc[mtd][nt] = __builtin_amdgcn_mfma_f32_16x16x32_f16(vv[pp][mtd], pb, Tacc[mtd][nt], 0, 0, 0);
                }
            }
            __builtin_amdgcn_s_setprio(0);
        }
    }
    // ---- column-sum partials (wave's 512 i-rows, 64 j) ----
    #pragma unroll
    for (int nt = 0; nt < 4; ++nt) {
        float s = scS[nt];
        s += __shfl_xor(s, 16);
        s += __shfl_xor(s, 32);
        if (q == 0) Ssh[w][nt * 16 + tx] = s;
    }
    // ---- per-wave T partial into TS[w], swizzled [64 j][64 d] ----
    #pragma unroll
    for (int mtd = 0; mtd < 4; ++mtd)
        #pragma unroll
        for (int nt = 0; nt < 4; ++nt) {
            f16x4 pkk;
            pkk[0] = (_Float16)Tacc[mtd][nt][0];
            pkk[1] = (_Float16)Tacc[mtd][nt][1];
            pkk[2] = (_Float16)Tacc[mtd][nt][2];
            pkk[3] = (_Float16)Tacc[mtd][nt][3];
            *(f16x4*)&TS[w][(nt * 16 + tx) * 64 + ((2 * mtd + (q >> 1)) ^ sx) * 8 + (q & 1) * 4] = pkk;
        }
    __syncthreads();
    // ---- reduce 4 i-chunk partials; u = h - T/S; direct XT write (2 slices/thread) ----
    {
        const int jl = tid >> 2, d4 = tid & 3;
        const float s4 = Ssh[0][jl] + Ssh[1][jl] + Ssh[2][jl] + Ssh[3][jl];
        const float rs = 1.f / s4;
        const int jg = j0 + jl;
        #pragma unroll
        for (int g = 0; g < 2; ++g) {
            const int s8 = d4 * 2 + g;
            const int base = jl * 64 + ((s8 ^ (jl & 7)) * 8);
            f16x8 t0 = *(const f16x8*)&TS[0][base];
            f16x8 t1 = *(const f16x8*)&TS[1][base];
            f16x8 t2 = *(const f16x8*)&TS[2][base];
            f16x8 t3 = *(const f16x8*)&TS[3][base];
            const float* hp = h + ((size_t)(b * Cch + hd * 64 + s8 * 8) * Npt) + jg;
            f16x8 u;
            #pragma unroll
            for (int e = 0; e < 8; ++e) {
                float tv = (float)t0[e] + (float)t1[e] + (float)t2[e] + (float)t3[e];
                u[e] = (_Float16)(hp[(size_t)e * Npt] - tv * rs);
            }
            *(f16x8*)(XT + ((size_t)(b * Npt + jg) * Cch) + hd * 64 + s8 * 8) = u;
        }
    }
}

extern "C" void kernel_launch(void* const* d_in, const int* in_sizes, int n_in,
                              void* d_out, int out_size, void* d_ws, size_t ws_size,
                              hipStream_t stream) {
    (void)in_sizes; (void)n_in; (void)out_size; (void)ws_size;
    const float* x    = (const float*)d_in[0];
    const float* xyz  = (const float*)d_in[1];
    const float* c1w  = (const float*)d_in[2];
    const float* posw = (const float*)d_in[3];
    const float* posb = (const float*)d_in[4];
    const float* bn1g = (const float*)d_in[5];
    const float* bn1b = (const float*)d_in[6];
    const float* qkw  = (const float*)d_in[7];
    const float* vw   = (const float*)d_in[8];
    const float* vb   = (const float*)d_in[9];
    const float* tw   = (const float*)d_in[10];
    const float* tb   = (const float*)d_in[11];
    const float* bng  = (const float*)d_in[12];
    const float* bnb  = (const float*)d_in[13];
    float* out = (float*)d_out;

    const size_t NE = (size_t)Bsz * Cch * Npt;   // 2,097,152
    char* W = (char*)d_ws;
    float* emb   = (float*)W;                 W += NE * 4;
    float* h     = (float*)W;                 W += NE * 4;
    _Float16* XT = (_Float16*)W;              W += NE * 2;
    _Float16* Qg = (_Float16*)W;              W += NE * 2;
    _Float16* Kt = (_Float16*)W;              W += NE * 2;
    _Float16* Vb = (_Float16*)W;              W += NE * 2;
    _Float16* wbf = (_Float16*)W;             W += 851968 * 2;
    float* mP    = (float*)W;                 W += 4 * NROW * 4;
    float* lP    = (float*)W;                 W += 4 * NROW * 4;
    float* bnacc = (float*)W;                 W += 5 * 512 * 4;   // 5 slots x (sum,sum2)
    unsigned* cnt = (unsigned*)W;             W += 5 * 4;         // 5 barrier counters

    dim3 blk(256);
    dim3 g4(Npt / 64, Cch / 64, Bsz);    // 32,4,4 = 512 blocks (== GB_BLOCKS)
    dim3 gQKV(Npt / 128, 8, Bsz);        // 16,8,4 — fused qk+v, 128-wide n tiles
    int ew = (int)(NE / 256);

    k_init<<<ew, blk, 0, stream>>>(xyz, posw, posb, emb, c1w, qkw, vw, tw, wbf, bnacc, cnt);

    // h0 = relu(bn1(conv1_w @ x)); XT = transpose(h0 + emb)
    k_fuse_t<<<g4, blk, 0, stream>>>(x, XT);
    k_gemm_bn<<<g4, blk, 0, stream>>>(wbf, XT, nullptr, bnacc, cnt + 0,
                                      bn1g, bn1b, emb, nullptr, h, nullptr, XT, 0);

    for (int L = 0; L < NL; ++L) {
        const _Float16* qkL = wbf + 65536 + (size_t)L * 65536;
        const _Float16* vL  = wbf + 327680 + (size_t)L * 65536;
        const _Float16* tL  = wbf + 589824 + (size_t)L * 65536;
        float* accL = bnacc + (1 + L) * 512;
        k_gemm_qkv<<<gQKV, blk, 0, stream>>>(qkL, vL, XT, vb + L * Cch, Vb, Qg, Kt);
        k_attn_A<<<1024, blk, 0, stream>>>(Qg, Kt, mP, lP);
        k_attn_B<<<512, blk, 0, stream>>>(Qg, Kt, Vb, mP, lP, h, XT);
        k_gemm_bn<<<g4, blk, 0, stream>>>(tL, XT, tb + L * Cch, accL, cnt + 1 + L,
                                          bng + L * Cch, bnb + L * Cch, emb, h, h, out, XT, L);
    }
}

// Round 13
// 539.222 us; speedup vs baseline: 1.2386x; 1.2133x over previous
//
#include <hip/hip_runtime.h>
#include <math.h>

#define Bsz 4
#define Cch 256
#define Npt 2048
#define Hh  4
#define NL  4
#define BN_CNT (Bsz * Npt)   // 8192
#define EPSV 1e-5f
#define NROW (16 * Npt)      // 32768 attention rows total (bh * Npt)
#define L2E 1.44269504f

typedef _Float16 f16x8 __attribute__((ext_vector_type(8)));
typedef _Float16 f16x4 __attribute__((ext_vector_type(4)));
typedef float    f32x4 __attribute__((ext_vector_type(4)));

__device__ __forceinline__ float fexp2(float x) { return __builtin_amdgcn_exp2f(x); }

// ---------------- init: xyz embedding + weight cast + bnacc zero (merged) ----------------
__global__ void k_init(const float* __restrict__ xyz, const float* __restrict__ pw,
                       const float* __restrict__ pb, float* __restrict__ emb,
                       const float* __restrict__ c1w, const float* __restrict__ qkw,
                       const float* __restrict__ vw, const float* __restrict__ tw,
                       _Float16* __restrict__ o, float* __restrict__ bnacc) {
    int idx = blockIdx.x * 256 + threadIdx.x;   // 0 .. NE-1 (2,097,152)
    int n = idx & (Npt - 1);
    int c = (idx >> 11) & (Cch - 1);
    int b = idx >> 19;
    const float* xz = xyz + (b * Npt + n) * 3;
    emb[idx] = pw[c * 3 + 0] * xz[0] + pw[c * 3 + 1] * xz[1] + pw[c * 3 + 2] * xz[2] + pb[c];
    if (idx < 5 * 512) bnacc[idx] = 0.f;     // 5 slots x (sum[256], sum2[256])
    if (idx < 851968) {
        const float* src; int off;
        if (idx < 65536)         { src = c1w; off = idx; }
        else if (idx < 327680)   { src = qkw; off = idx - 65536; }
        else if (idx < 589824)   { src = vw;  off = idx - 327680; }
        else                     { src = tw;  off = idx - 589824; }
        o[idx] = (_Float16)src[off];
    }
}

// ---------------- transpose + cast x -> XT[b][n][c] (entry only) ----------------
__global__ __launch_bounds__(256) void k_fuse_t(const float* __restrict__ in,
        _Float16* __restrict__ XT) {
    __shared__ _Float16 Tt[64][72];
    const int b = blockIdx.z, c0 = blockIdx.y * 64, n0 = blockIdx.x * 64;
    const int t = threadIdx.x;
    const int cl = t >> 2, ns = (t & 3) * 16;
    const float* ip = in + ((size_t)(b * Cch + c0 + cl) * Npt) + n0 + ns;
    #pragma unroll
    for (int g = 0; g < 4; ++g) {
        float4 v = *(const float4*)(ip + g * 4);
        Tt[ns + g * 4 + 0][cl] = (_Float16)v.x;
        Tt[ns + g * 4 + 1][cl] = (_Float16)v.y;
        Tt[ns + g * 4 + 2][cl] = (_Float16)v.z;
        Tt[ns + g * 4 + 3][cl] = (_Float16)v.w;
    }
    __syncthreads();
    int nl = t >> 2, cs = (t & 3) * 16;
    _Float16* op = XT + ((size_t)(b * Npt + n0 + nl) * Cch) + c0 + cs;
    #pragma unroll
    for (int g = 0; g < 4; ++g)
        *(f16x4*)(op + g * 4) = *(f16x4*)&Tt[nl][cs + g * 4];
}

// ---------------- MFMA GEMM (fp32 out) + fused BN partial-stat atomics ----------------
// (Split gemm->vbuf->bn restored: R10-R12 proved the in-kernel device barrier costs
// ~30us/invocation more than this kernel-boundary -- the boundary IS the cheap barrier.)
__global__ __launch_bounds__(256) void k_gemm_mfma(const _Float16* __restrict__ Wb,
        const _Float16* __restrict__ XT, const float* __restrict__ bias,
        float* __restrict__ Yf, float* __restrict__ bnacc) {
    __shared__ float EpF[64][68];
    const int b = blockIdx.z, o0 = blockIdx.y * 64, n0 = blockIdx.x * 64;
    const int tid = threadIdx.x, w = tid >> 6, quad = (tid >> 4) & 3, tx = tid & 15;
    const _Float16* Arow = Wb + (o0 + w * 16 + tx) * Cch + quad * 8;
    const _Float16* Brow = XT + ((size_t)(b * Npt + n0 + tx) * Cch) + quad * 8;
    f32x4 acc[4];
    #pragma unroll
    for (int s = 0; s < 4; ++s) acc[s] = (f32x4){0.f, 0.f, 0.f, 0.f};
    for (int k0 = 0; k0 < Cch; k0 += 32) {
        f16x8 a = *(const f16x8*)(Arow + k0);
        #pragma unroll
        for (int s = 0; s < 4; ++s) {
            f16x8 bb = *(const f16x8*)(Brow + s * 16 * Cch + k0);
            acc[s] = __builtin_amdgcn_mfma_f32_16x16x32_f16(a, bb, acc[s], 0, 0, 0);
        }
    }
    float bv[4];
    {
        int ob = o0 + w * 16 + quad * 4;
        if (bias) { bv[0] = bias[ob]; bv[1] = bias[ob + 1]; bv[2] = bias[ob + 2]; bv[3] = bias[ob + 3]; }
        else bv[0] = bv[1] = bv[2] = bv[3] = 0.f;
    }
    #pragma unroll
    for (int s = 0; s < 4; ++s) {
        int ol = w * 16 + quad * 4, nl = s * 16 + tx;
        EpF[ol + 0][nl] = acc[s][0] + bv[0];
        EpF[ol + 1][nl] = acc[s][1] + bv[1];
        EpF[ol + 2][nl] = acc[s][2] + bv[2];
        EpF[ol + 3][nl] = acc[s][3] + bv[3];
    }
    __syncthreads();
    int row = tid >> 2, seg = (tid & 3) * 16;
    float* yp = Yf + ((size_t)(b * Cch + o0 + row) * Npt) + n0 + seg;
    float s1 = 0.f, s2 = 0.f;
    #pragma unroll
    for (int g = 0; g < 4; ++g) {
        float4 v = *(float4*)&EpF[row][seg + g * 4];
        *(float4*)(yp + g * 4) = v;
        s1 += v.x + v.y + v.z + v.w;
        s2 += v.x * v.x + v.y * v.y + v.z * v.z + v.w * v.w;
    }
    s1 += __shfl_xor(s1, 1); s2 += __shfl_xor(s2, 1);
    s1 += __shfl_xor(s1, 2); s2 += __shfl_xor(s2, 2);
    if ((tid & 3) == 0) {
        atomicAdd(&bnacc[o0 + row], s1);
        atomicAdd(&bnacc[256 + o0 + row], s2);
    }
}

// ---------------- fused qk + v GEMM, 64o x 128n tiles: y<4 -> Qg/Kt (swizzled),
// y>=4 -> Vb fp16 (permuted columns). Grid (16,8,4)=512, 2 blocks/CU.
__global__ __launch_bounds__(256) void k_gemm_qkv(const _Float16* __restrict__ Wqk,
        const _Float16* __restrict__ Wv, const _Float16* __restrict__ XT,
        const float* __restrict__ vbias, _Float16* __restrict__ Vb,
        _Float16* __restrict__ Qg, _Float16* __restrict__ Kt) {
    __shared__ _Float16 EpB[64][136];
    const int b = blockIdx.z, y = blockIdx.y, n0 = blockIdx.x * 128;
    const int isV = (y >= 4);
    const int o0 = (isV ? (y - 4) : y) * 64;
    const _Float16* Wb = isV ? Wv : Wqk;
    const int tid = threadIdx.x, w = tid >> 6, quad = (tid >> 4) & 3, tx = tid & 15;
    const _Float16* Arow = Wb + (o0 + w * 16 + tx) * Cch + quad * 8;
    const _Float16* Brow = XT + ((size_t)(b * Npt + n0 + tx) * Cch) + quad * 8;
    f32x4 acc[8];
    #pragma unroll
    for (int s = 0; s < 8; ++s) acc[s] = (f32x4){0.f, 0.f, 0.f, 0.f};
    for (int k0 = 0; k0 < Cch; k0 += 32) {
        f16x8 a = *(const f16x8*)(Arow + k0);
        #pragma unroll
        for (int s = 0; s < 8; ++s) {
            f16x8 bb = *(const f16x8*)(Brow + s * 16 * Cch + k0);
            acc[s] = __builtin_amdgcn_mfma_f32_16x16x32_f16(a, bb, acc[s], 0, 0, 0);
        }
    }
    if (!isV) {
        const int cch = (w << 1) + (quad >> 1);
        const int hof = (quad & 1) * 4;
        #pragma unroll
        for (int s = 0; s < 8; ++s) {
            int ng = n0 + s * 16 + tx;
            f16x4 pk;
            pk[0] = (_Float16)acc[s][0]; pk[1] = (_Float16)acc[s][1];
            pk[2] = (_Float16)acc[s][2]; pk[3] = (_Float16)acc[s][3];
            int rK = ng & 63, jt = ng >> 6;
            size_t ka = ((size_t)((b * Hh + (o0 >> 6)) * 32 + jt) << 12)
                      + rK * 64 + ((cch ^ (rK & 7)) * 8) + hof;
            *(f16x4*)&Kt[ka] = pk;
            int iQ = ((ng & 511) << 2) + (o0 >> 6);
            int rQ = iQ & 63, it = iQ >> 6;
            size_t qa = ((size_t)((b * Hh + (ng >> 9)) * 32 + it) << 12)
                      + rQ * 64 + ((cch ^ (rQ & 7)) * 8) + hof;
            *(f16x4*)&Qg[qa] = pk;
        }
        return;
    }
    float bv[4];
    {
        int ob = o0 + w * 16 + quad * 4;
        bv[0] = vbias[ob]; bv[1] = vbias[ob + 1]; bv[2] = vbias[ob + 2]; bv[3] = vbias[ob + 3];
    }
    #pragma unroll
    for (int s = 0; s < 8; ++s) {
        int ol = w * 16 + quad * 4, nl = s * 16 + tx;
        EpB[ol + 0][nl] = (_Float16)(acc[s][0] + bv[0]);
        EpB[ol + 1][nl] = (_Float16)(acc[s][1] + bv[1]);
        EpB[ol + 2][nl] = (_Float16)(acc[s][2] + bv[2]);
        EpB[ol + 3][nl] = (_Float16)(acc[s][3] + bv[3]);
    }
    __syncthreads();
    int row = tid >> 2;
    const int m = tid & 3;
    const int pbase = (m >> 1) * 32 + (m & 1) * 4;
    const int seg = m * 16;
    #pragma unroll
    for (int half = 0; half < 2; ++half) {
        _Float16* yp = Vb + ((size_t)(b * Cch + o0 + row) * Npt) + n0 + half * 64 + pbase;
        #pragma unroll
        for (int g = 0; g < 4; ++g)
            *(f16x4*)(yp + g * 8) = *(f16x4*)&EpB[row][half * 64 + seg + g * 4];
    }
}

// ---------------- attention pass A: 128 i-rows/block, register-resident K, no LDS,
// no barriers. Grid 1024, XCD-aware remap.
__global__ __launch_bounds__(256, 3) void k_attn_A(const _Float16* __restrict__ Qg,
        const _Float16* __restrict__ Kt, float* __restrict__ mP, float* __restrict__ lP) {
    const int flat = blockIdx.x;
    const int bh = (flat & 7) * 2 + ((flat >> 3) & 1);
    const int rest = flat >> 4;              // 0..63
    const int i0 = (rest & 15) * 128;
    const int jc = rest >> 4;                // 0..3
    const int tid = threadIdx.x, w = tid >> 6, q = (tid >> 4) & 3, tx = tid & 15;
    const int sx = tx & 7;
    f16x8 qa[2][2];
    #pragma unroll
    for (int g = 0; g < 2; ++g) {
        const _Float16* Qtile = Qg + ((size_t)(bh * 32 + ((i0 + g * 64) >> 6)) << 12);
        int r = w * 16 + tx;
        qa[g][0] = *(const f16x8*)(Qtile + r * 64 + (q ^ sx) * 8);
        qa[g][1] = *(const f16x8*)(Qtile + r * 64 + ((q + 4) ^ sx) * 8);
    }
    const _Float16* Kbase = Kt + ((size_t)(bh * 32) << 12);
    const int jt0 = jc * 8;
    float m2[2][4], l[2][4];
    #pragma unroll
    for (int g = 0; g < 2; ++g)
        #pragma unroll
        for (int r = 0; r < 4; ++r) { m2[g][r] = -1e30f; l[g][r] = 0.f; }
    for (int t = 0; t < 8; ++t) {
        const _Float16* kpage = Kbase + ((size_t)(jt0 + t) << 12);
        f16x8 kb0[4], kb1[4];
        #pragma unroll
        for (int s = 0; s < 4; ++s) {
            int r = s * 16 + tx;
            kb0[s] = *(const f16x8*)(kpage + r * 64 + (q ^ sx) * 8);
            kb1[s] = *(const f16x8*)(kpage + r * 64 + ((q + 4) ^ sx) * 8);
        }
        #pragma unroll
        for (int g = 0; g < 2; ++g) {
            f32x4 e[4];
            __builtin_amdgcn_s_setprio(1);
            #pragma unroll
            for (int s = 0; s < 4; ++s) {
                f32x4 z = (f32x4){0.f, 0.f, 0.f, 0.f};
                z = __builtin_amdgcn_mfma_f32_16x16x32_f16(qa[g][0], kb0[s], z, 0, 0, 0);
                e[s] = __builtin_amdgcn_mfma_f32_16x16x32_f16(qa[g][1], kb1[s], z, 0, 0, 0);
            }
            __builtin_amdgcn_s_setprio(0);
            #pragma unroll
            for (int r = 0; r < 4; ++r) {
                float e0 = e[0][r] * L2E, e1 = e[1][r] * L2E;
                float e2 = e[2][r] * L2E, e3 = e[3][r] * L2E;
                float lm = fmaxf(fmaxf(e0, e1), fmaxf(e2, e3));
                float nm = fmaxf(m2[g][r], lm);
                l[g][r] = l[g][r] * fexp2(m2[g][r] - nm)
                        + fexp2(e0 - nm) + fexp2(e1 - nm) + fexp2(e2 - nm) + fexp2(e3 - nm);
                m2[g][r] = nm;
            }
        }
    }
    #pragma unroll
    for (int g = 0; g < 2; ++g)
        #pragma unroll
        for (int r = 0; r < 4; ++r) {
            float mm = m2[g][r], ll = l[g][r];
            #pragma unroll
            for (int off = 1; off < 16; off <<= 1) {
                float om = __shfl_xor(mm, off), ol = __shfl_xor(ll, off);
                float nm = fmaxf(mm, om);
                ll = ll * fexp2(mm - nm) + ol * fexp2(om - nm);
                mm = nm;
            }
            if (tx == 0) {
                int idx = bh * Npt + i0 + g * 64 + w * 16 + q * 4 + r;
                mP[jc * NROW + idx] = mm;
                lP[jc * NROW + idx] = ll;
            }
        }
}

// ---------------- attention pass B: traffic-minimal shape (256 thr / 4 waves, grid 512,
// wave = FULL j=64 x 512 i) + in-register PV (permuted Vb) + hoisted Q/V loads +
// setprio around PV. ~195 VGPR, fits (256,2)'s 256. Bit-identical output.
__global__ __launch_bounds__(256, 2) void k_attn_B(const _Float16* __restrict__ Qg,
        const _Float16* __restrict__ Kt, const _Float16* __restrict__ Vb,
        const float* __restrict__ mP, const float* __restrict__ lP,
        const float* __restrict__ h, _Float16* __restrict__ XT) {
    __shared__ float mlm[Npt];            // fused mlcomb: row max (base-2)
    __shared__ float mll[Npt];            // fused mlcomb: L2E / l
    __shared__ float Ssh[4][64];          // per-wave column-sum partials
    __shared__ _Float16 TS[4][4096];      // 32KB: per-wave [64 j][64 d] swizzled T-partial
    const int flat = blockIdx.x;
    const int bh = (flat & 7) * 2 + ((flat >> 3) & 1);
    const int j0 = (flat >> 4) * 64;
    const int b = bh >> 2, hd = bh & 3;
    const int tid = threadIdx.x, w = tid >> 6, q = (tid >> 4) & 3, tx = tid & 15;
    const int sx = tx & 7;
    // ---- fused mlcomb: combine 4 j-chunk (m,l) partials for this bh into LDS ----
    {
        const int ib = tid * 8;
        #pragma unroll
        for (int e = 0; e < 2; ++e) {
            int ii = ib + e * 4;
            int idx = bh * Npt + ii;
            float4 m0 = *(const float4*)&mP[idx];
            float4 m1 = *(const float4*)&mP[NROW + idx];
            float4 m2 = *(const float4*)&mP[2 * NROW + idx];
            float4 m3 = *(const float4*)&mP[3 * NROW + idx];
            float4 l0 = *(const float4*)&lP[idx];
            float4 l1 = *(const float4*)&lP[NROW + idx];
            float4 l2 = *(const float4*)&lP[2 * NROW + idx];
            float4 l3 = *(const float4*)&lP[3 * NROW + idx];
            #pragma unroll
            for (int k = 0; k < 4; ++k) {
                float a0 = ((const float*)&m0)[k], a1 = ((const float*)&m1)[k];
                float a2 = ((const float*)&m2)[k], a3 = ((const float*)&m3)[k];
                float mm = fmaxf(fmaxf(a0, a1), fmaxf(a2, a3));
                float ll = ((const float*)&l0)[k] * fexp2(a0 - mm)
                         + ((const float*)&l1)[k] * fexp2(a1 - mm)
                         + ((const float*)&l2)[k] * fexp2(a2 - mm)
                         + ((const float*)&l3)[k] * fexp2(a3 - mm);
                mlm[ii + k] = mm;
                mll[ii + k] = L2E / ll;
            }
        }
    }
    // ---- K fragments for the full 64-j tile (register-resident, 32 VGPR) ----
    f16x8 kb[4][2];
    {
        const _Float16* Ktile = Kt + ((size_t)(bh * 32 + (j0 >> 6)) << 12);
        #pragma unroll
        for (int nt = 0; nt < 4; ++nt) {
            int r = nt * 16 + tx;
            kb[nt][0] = *(const f16x8*)(Ktile + r * 64 + (q ^ sx) * 8);
            kb[nt][1] = *(const f16x8*)(Ktile + r * 64 + ((q + 4) ^ sx) * 8);
        }
    }
    __syncthreads();
    f32x4 Tacc[4][4];
    #pragma unroll
    for (int mt = 0; mt < 4; ++mt)
        #pragma unroll
        for (int nt = 0; nt < 4; ++nt) Tacc[mt][nt] = (f32x4){0.f, 0.f, 0.f, 0.f};
    float scS[4] = {0.f, 0.f, 0.f, 0.f};
    const _Float16* vbase = Vb + (size_t)(b * Cch + hd * 64) * Npt;
    for (int it = 0; it < 8; ++it) {
        const int i0 = w * 512 + it * 64;
        const _Float16* Qtile = Qg + ((size_t)(bh * 32 + (i0 >> 6)) << 12);
        // ---- issue ALL of this iteration's Q and V loads up front ----
        f16x8 qv[2][2][2];   // [pp][mt2][half]
        f16x8 vv[2][4];      // [pp][mtd]
        #pragma unroll
        for (int pp = 0; pp < 2; ++pp) {
            #pragma unroll
            for (int mt2 = 0; mt2 < 2; ++mt2) {
                const int r = (pp * 2 + mt2) * 16 + tx;
                qv[pp][mt2][0] = *(const f16x8*)(Qtile + r * 64 + (q ^ sx) * 8);
                qv[pp][mt2][1] = *(const f16x8*)(Qtile + r * 64 + ((q + 4) ^ sx) * 8);
            }
            #pragma unroll
            for (int mtd = 0; mtd < 4; ++mtd)
                vv[pp][mtd] = *(const f16x8*)(vbase + (size_t)(mtd * 16 + tx) * Npt + i0 + pp * 32 + q * 8);
        }
        #pragma unroll
        for (int pp = 0; pp < 2; ++pp) {
            f16x4 pk[2][4];
            #pragma unroll
            for (int mt2 = 0; mt2 < 2; ++mt2) {
                const int mt = pp * 2 + mt2;
                float4 m2v = *(const float4*)&mlm[i0 + mt * 16 + q * 4];
                float4 liv = *(const float4*)&mll[i0 + mt * 16 + q * 4];
                #pragma unroll
                for (int nt = 0; nt < 4; ++nt) {
                    f32x4 z = (f32x4){0.f, 0.f, 0.f, 0.f};
                    z = __builtin_amdgcn_mfma_f32_16x16x32_f16(qv[pp][mt2][0], kb[nt][0], z, 0, 0, 0);
                    z = __builtin_amdgcn_mfma_f32_16x16x32_f16(qv[pp][mt2][1], kb[nt][1], z, 0, 0, 0);
                    float a0 = fexp2(fexp2(__builtin_fmaf(z[0], L2E, -m2v.x)) * liv.x);
                    float a1 = fexp2(fexp2(__builtin_fmaf(z[1], L2E, -m2v.y)) * liv.y);
                    float a2 = fexp2(fexp2(__builtin_fmaf(z[2], L2E, -m2v.z)) * liv.z);
                    float a3 = fexp2(fexp2(__builtin_fmaf(z[3], L2E, -m2v.w)) * liv.w);
                    scS[nt] += a0 + a1 + a2 + a3;
                    f16x4 pkk;
                    pkk[0] = (_Float16)a0; pkk[1] = (_Float16)a1;
                    pkk[2] = (_Float16)a2; pkk[3] = (_Float16)a3;
                    pk[mt2][nt] = pkk;
                }
            }
            __builtin_amdgcn_s_setprio(1);
            #pragma unroll
            for (int mtd = 0; mtd < 4; ++mtd) {
                #pragma unroll
                for (int nt = 0; nt < 4; ++nt) {
                    f16x8 pb = __builtin_shufflevector(pk[0][nt], pk[1][nt], 0, 1, 2, 3, 4, 5, 6, 7);
                    Tacc[mtd][nt] = __builtin_amdgcn_mfma_f32_16x16x32_f16(vv[pp][mtd], pb, Tacc[mtd][nt], 0, 0, 0);
                }
            }
            __builtin_amdgcn_s_setprio(0);
        }
    }
    // ---- column-sum partials (wave's 512 i-rows, 64 j) ----
    #pragma unroll
    for (int nt = 0; nt < 4; ++nt) {
        float s = scS[nt];
        s += __shfl_xor(s, 16);
        s += __shfl_xor(s, 32);
        if (q == 0) Ssh[w][nt * 16 + tx] = s;
    }
    // ---- per-wave T partial into TS[w], swizzled [64 j][64 d] ----
    #pragma unroll
    for (int mtd = 0; mtd < 4; ++mtd)
        #pragma unroll
        for (int nt = 0; nt < 4; ++nt) {
            f16x4 pkk;
            pkk[0] = (_Float16)Tacc[mtd][nt][0];
            pkk[1] = (_Float16)Tacc[mtd][nt][1];
            pkk[2] = (_Float16)Tacc[mtd][nt][2];
            pkk[3] = (_Float16)Tacc[mtd][nt][3];
            *(f16x4*)&TS[w][(nt * 16 + tx) * 64 + ((2 * mtd + (q >> 1)) ^ sx) * 8 + (q & 1) * 4] = pkk;
        }
    __syncthreads();
    // ---- reduce 4 i-chunk partials; u = h - T/S; direct XT write (2 slices/thread) ----
    {
        const int jl = tid >> 2, d4 = tid & 3;
        const float s4 = Ssh[0][jl] + Ssh[1][jl] + Ssh[2][jl] + Ssh[3][jl];
        const float rs = 1.f / s4;
        const int jg = j0 + jl;
        #pragma unroll
        for (int g = 0; g < 2; ++g) {
            const int s8 = d4 * 2 + g;
            const int base = jl * 64 + ((s8 ^ (jl & 7)) * 8);
            f16x8 t0 = *(const f16x8*)&TS[0][base];
            f16x8 t1 = *(const f16x8*)&TS[1][base];
            f16x8 t2 = *(const f16x8*)&TS[2][base];
            f16x8 t3 = *(const f16x8*)&TS[3][base];
            const float* hp = h + ((size_t)(b * Cch + hd * 64 + s8 * 8) * Npt) + jg;
            f16x8 u;
            #pragma unroll
            for (int e = 0; e < 8; ++e) {
                float tv = (float)t0[e] + (float)t1[e] + (float)t2[e] + (float)t3[e];
                u[e] = (_Float16)(hp[(size_t)e * Npt] - tv * rs);
            }
            *(f16x8*)(XT + ((size_t)(b * Npt + jg) * Cch) + hd * 64 + s8 * 8) = u;
        }
    }
}

// ---- fused BN(from atomically-accumulated stats) + relu + residual + out + transpose -> XT ----
__global__ __launch_bounds__(256) void k_bn_fuse(const float* __restrict__ t,
        const float* __restrict__ bnacc,
        const float* __restrict__ g, const float* __restrict__ bt,
        const float* __restrict__ emb, const float* __restrict__ resid,
        float* __restrict__ hout, float* __restrict__ out, _Float16* __restrict__ XT,
        int layer) {
    __shared__ _Float16 Tt[64][72];
    const int b = blockIdx.z, c0 = blockIdx.y * 64, n0 = blockIdx.x * 64;
    const int tt = threadIdx.x;
    const int cl = tt >> 2, ns = (tt & 3) * 16;
    const int c = c0 + cl;
    const float mn = bnacc[c] * (1.f / BN_CNT);
    const float var = bnacc[256 + c] * (1.f / BN_CNT) - mn * mn;
    const float is = rsqrtf(var + EPSV);
    const float gg = g[c], bb = bt[c];
    const size_t rowoff = ((size_t)(b * Cch + c) * Npt) + n0 + ns;
    const float* tp = t + rowoff;
    const float* ep = emb + rowoff;
    const float* rp = resid ? resid + rowoff : nullptr;
    float* hp = hout + rowoff;
    float* op = out ? out + (size_t)b * (NL * Cch * Npt) + (size_t)(layer * Cch + c) * Npt + n0 + ns
                    : nullptr;
    #pragma unroll
    for (int gi = 0; gi < 4; ++gi) {
        float4 v = *(const float4*)(tp + gi * 4);
        float4 y;
        y.x = fmaxf(gg * (v.x - mn) * is + bb, 0.f);
        y.y = fmaxf(gg * (v.y - mn) * is + bb, 0.f);
        y.z = fmaxf(gg * (v.z - mn) * is + bb, 0.f);
        y.w = fmaxf(gg * (v.w - mn) * is + bb, 0.f);
        if (rp) {
            float4 r = *(const float4*)(rp + gi * 4);
            y.x += r.x; y.y += r.y; y.z += r.z; y.w += r.w;
        }
        *(float4*)(hp + gi * 4) = y;
        if (op) *(float4*)(op + gi * 4) = y;
        float4 e = *(const float4*)(ep + gi * 4);
        Tt[ns + gi * 4 + 0][cl] = (_Float16)(y.x + e.x);
        Tt[ns + gi * 4 + 1][cl] = (_Float16)(y.y + e.y);
        Tt[ns + gi * 4 + 2][cl] = (_Float16)(y.z + e.z);
        Tt[ns + gi * 4 + 3][cl] = (_Float16)(y.w + e.w);
    }
    __syncthreads();
    int nl = tt >> 2, cs = (tt & 3) * 16;
    _Float16* xp = XT + ((size_t)(b * Npt + n0 + nl) * Cch) + c0 + cs;
    #pragma unroll
    for (int gi = 0; gi < 4; ++gi)
        *(f16x4*)(xp + gi * 4) = *(f16x4*)&Tt[nl][cs + gi * 4];
}

extern "C" void kernel_launch(void* const* d_in, const int* in_sizes, int n_in,
                              void* d_out, int out_size, void* d_ws, size_t ws_size,
                              hipStream_t stream) {
    (void)in_sizes; (void)n_in; (void)out_size; (void)ws_size;
    const float* x    = (const float*)d_in[0];
    const float* xyz  = (const float*)d_in[1];
    const float* c1w  = (const float*)d_in[2];
    const float* posw = (const float*)d_in[3];
    const float* posb = (const float*)d_in[4];
    const float* bn1g = (const float*)d_in[5];
    const float* bn1b = (const float*)d_in[6];
    const float* qkw  = (const float*)d_in[7];
    const float* vw   = (const float*)d_in[8];
    const float* vb   = (const float*)d_in[9];
    const float* tw   = (const float*)d_in[10];
    const float* tb   = (const float*)d_in[11];
    const float* bng  = (const float*)d_in[12];
    const float* bnb  = (const float*)d_in[13];
    float* out = (float*)d_out;

    const size_t NE = (size_t)Bsz * Cch * Npt;   // 2,097,152
    char* W = (char*)d_ws;
    float* emb   = (float*)W;                 W += NE * 4;
    float* h     = (float*)W;                 W += NE * 4;
    float* vbuf  = (float*)W;                 W += NE * 4;   // fp32 conv outputs
    _Float16* XT = (_Float16*)W;              W += NE * 2;
    _Float16* Qg = (_Float16*)W;              W += NE * 2;
    _Float16* Kt = (_Float16*)W;              W += NE * 2;
    _Float16* Vb = (_Float16*)W;              W += NE * 2;
    _Float16* wbf = (_Float16*)W;             W += 851968 * 2;
    float* mP    = (float*)W;                 W += 4 * NROW * 4;
    float* lP    = (float*)W;                 W += 4 * NROW * 4;
    float* bnacc = (float*)W;                 W += 5 * 512 * 4;   // 5 slots x (sum,sum2)

    dim3 blk(256);
    dim3 g4(Npt / 64, Cch / 64, Bsz);    // 32,4,4
    dim3 gQKV(Npt / 128, 8, Bsz);        // 16,8,4 — fused qk+v, 128-wide n tiles
    int ew = (int)(NE / 256);

    k_init<<<ew, blk, 0, stream>>>(xyz, posw, posb, emb, c1w, qkw, vw, tw, wbf, bnacc);

    // h0 = relu(bn1(conv1_w @ x)); XT = transpose(h0 + emb)
    k_fuse_t<<<g4, blk, 0, stream>>>(x, XT);
    k_gemm_mfma<<<g4, blk, 0, stream>>>(wbf, XT, nullptr, vbuf, bnacc);
    k_bn_fuse<<<g4, blk, 0, stream>>>(vbuf, bnacc, bn1g, bn1b, emb, nullptr,
                                      h, nullptr, XT, 0);

    for (int L = 0; L < NL; ++L) {
        const _Float16* qkL = wbf + 65536 + (size_t)L * 65536;
        const _Float16* vL  = wbf + 327680 + (size_t)L * 65536;
        const _Float16* tL  = wbf + 589824 + (size_t)L * 65536;
        float* accL = bnacc + (1 + L) * 512;
        k_gemm_qkv<<<gQKV, blk, 0, stream>>>(qkL, vL, XT, vb + L * Cch, Vb, Qg, Kt);
        k_attn_A<<<1024, blk, 0, stream>>>(Qg, Kt, mP, lP);
        k_attn_B<<<512, blk, 0, stream>>>(Qg, Kt, Vb, mP, lP, h, XT);
        k_gemm_mfma<<<g4, blk, 0, stream>>>(tL, XT, tb + L * Cch, vbuf, accL);
        k_bn_fuse<<<g4, blk, 0, stream>>>(vbuf, accL, bng + L * Cch, bnb + L * Cch,
                                          emb, h, h, out, XT, L);
    }
}